// Round 8
// baseline (422.078 us; speedup 1.0000x reference)
//
#include <hip/hip_runtime.h>

#define NN      100000
#define NE      3200000
#define NHALF   50000               // src-range split for L2 locality
#define IN_DIM  256
#define HID     64
#define ODIM    32
#define BSZ     128                 // nodes per bucket (dst>>7)
#define NB      782                 // ceil(NN / BSZ)
#define CAP     4608                // max edges/bucket: mean 4096, sd ~64 -> +8 sigma
#define CHUNK   4096                // edges per binning block
#define NGEMM1  1563                // ceil(NN / 64)
#define NBIN    782                 // ceil(NE / CHUNK)

typedef __attribute__((ext_vector_type(8))) short bf16x8;
typedef __attribute__((ext_vector_type(4))) float f32x4;

__device__ __forceinline__ unsigned bf16_rne(float f) {
    unsigned u = __float_as_uint(f);
    return (u + 0x7fffu + ((u >> 16) & 1u)) >> 16;
}

// ---------------- edge dtype detection (int64 vs int32) ----------------
__global__ void k_detect(const unsigned* __restrict__ e, int* __restrict__ flag) {
    unsigned d = e[2u * threadIdx.x + 1u];
    if (d != 0u) atomicOr(flag, 1);   // any nonzero high-dword => int32 layout
}

__global__ void k_initcur(int* __restrict__ cursor) {
    int i = blockIdx.x * blockDim.x + threadIdx.x;
    if (i < NB) cursor[i] = i * CAP;
}

// ---------------- fused kernel 1: MFMA GEMM1 blocks + bin blocks ----------------
__device__ void bin_block(int bb, const void* __restrict__ ev, const int* __restrict__ flag,
                          int* __restrict__ cursor, unsigned* __restrict__ ebuf, char* smem) {
    unsigned* el        = (unsigned*)smem;                 // [4096] 16 KB packed
    unsigned short* bk  = (unsigned short*)(smem + 16384); // [4096]  8 KB bucket ids
    int* hist           = (int*)(smem + 24576);            // [782]
    int* gbase          = (int*)(smem + 27712);            // [782]  => 30.8 KB
    int t = threadIdx.x;
    for (int i = t; i < NB; i += 256) hist[i] = 0;
    __syncthreads();
    bool is64 = (*flag == 0);
    long long base = (long long)bb * CHUNK;
#pragma unroll
    for (int j = 0; j < CHUNK / 256; ++j) {
        int li = j * 256 + t;
        long long idx = base + li;
        if (idx < NE) {
            int s, d;
            if (is64) {
                s = (int)((const long long*)ev)[idx];
                d = (int)((const long long*)ev)[NE + idx];
            } else {
                s = ((const int*)ev)[idx];
                d = ((const int*)ev)[NE + idx];
            }
            el[li] = ((unsigned)s << 7) | (unsigned)(d & 127);
            int bu = d >> 7;
            bk[li] = (unsigned short)bu;
            atomicAdd(&hist[bu], 1);
        }
    }
    __syncthreads();
    for (int u = t; u < NB; u += 256) {
        int c = hist[u];
        gbase[u] = c ? atomicAdd(&cursor[u], c) : 0;   // claim contiguous run
        hist[u] = 0;                                   // reuse as local offset
    }
    __syncthreads();
#pragma unroll
    for (int j = 0; j < CHUNK / 256; ++j) {
        int li = j * 256 + t;
        long long idx = base + li;
        if (idx < NE) {
            int bu = bk[li];
            int p = gbase[bu] + atomicAdd(&hist[bu], 1);
            if (p < (bu + 1) * CAP)                    // safety; never triggers
                ebuf[p] = el[li];
        }
    }
}

// MFMA GEMM: 64x64 tile, K-tile 128, wave w owns rows 16w..16w+15, 4 col-frags.
// LDS: xs[64][136] bf16 row-major, wt[64][136] bf16 = W1^T (n-major, k contiguous).
#define LSTR 136
__device__ void gemm1_block(int gid, const float* __restrict__ x,
                            const float* __restrict__ W1, unsigned* __restrict__ h1raw,
                            char* smem) {
    short* xs = (short*)smem;              // 17408 B
    short* wt = (short*)(smem + 17408);    // 17408 B => 34816 B total
    int t = threadIdx.x;
    int w = t >> 6, l = t & 63;
    int l15 = l & 15, g = l >> 4;
    int rowBase = gid * 64;
    f32x4 acc[4];
#pragma unroll
    for (int ct = 0; ct < 4; ++ct) acc[ct] = (f32x4){0.f, 0.f, 0.f, 0.f};

    for (int kt = 0; kt < IN_DIM; kt += 128) {
        __syncthreads();
#pragma unroll
        for (int p = 0; p < 8; ++p) {          // stage x: 64 rows x 128 k -> bf16
            int fid = p * 256 + t;
            int r = fid >> 5, c4 = fid & 31;
            int gr = rowBase + r; if (gr >= NN) gr = NN - 1;
            float4 v = *(const float4*)&x[(size_t)gr * IN_DIM + kt + c4 * 4];
            *(unsigned*)&xs[r * LSTR + c4 * 4]     = bf16_rne(v.x) | (bf16_rne(v.y) << 16);
            *(unsigned*)&xs[r * LSTR + c4 * 4 + 2] = bf16_rne(v.z) | (bf16_rne(v.w) << 16);
        }
#pragma unroll
        for (int p = 0; p < 8; ++p) {          // stage W1^T: coalesced k-rows, scatter n-rows
            int n = t & 63, kb = (t >> 6) * 4 + p * 16;
            float v0 = W1[(size_t)(kt + kb + 0) * HID + n];
            float v1 = W1[(size_t)(kt + kb + 1) * HID + n];
            float v2 = W1[(size_t)(kt + kb + 2) * HID + n];
            float v3 = W1[(size_t)(kt + kb + 3) * HID + n];
            *(unsigned*)&wt[n * LSTR + kb]     = bf16_rne(v0) | (bf16_rne(v1) << 16);
            *(unsigned*)&wt[n * LSTR + kb + 2] = bf16_rne(v2) | (bf16_rne(v3) << 16);
        }
        __syncthreads();
#pragma unroll
        for (int step = 0; step < 4; ++step) { // K=32 per step
            int ko = step * 32 + g * 8;        // lane's k-chunk (16B aligned)
            bf16x8 a = *(const bf16x8*)&xs[(w * 16 + l15) * LSTR + ko];
#pragma unroll
            for (int ct = 0; ct < 4; ++ct) {
                bf16x8 b = *(const bf16x8*)&wt[(ct * 16 + l15) * LSTR + ko];
                acc[ct] = __builtin_amdgcn_mfma_f32_16x16x32_bf16(a, b, acc[ct], 0, 0, 0);
            }
        }
    }
    // D: row=(l>>4)*4+reg, col=ct*16+(l&15); pack bf16 pairs via neighbor shfl
#pragma unroll
    for (int ct = 0; ct < 4; ++ct) {
#pragma unroll
        for (int r = 0; r < 4; ++r) {
            float v = acc[ct][r];
            float vn = __shfl_xor(v, 1, 64);   // col+1 (same row: l15 even)
            int gr = rowBase + w * 16 + g * 4 + r;
            if ((l15 & 1) == 0 && gr < NN)
                h1raw[(size_t)gr * 32 + ct * 8 + (l15 >> 1)] =
                    bf16_rne(v) | (bf16_rne(vn) << 16);
        }
    }
}

__global__ __launch_bounds__(256, 4) void k_fuse1(const float* __restrict__ x,
                                                  const float* __restrict__ W1,
                                                  unsigned* __restrict__ h1raw,
                                                  const void* __restrict__ ev,
                                                  const int* __restrict__ flag,
                                                  int* __restrict__ cursor,
                                                  unsigned* __restrict__ ebuf) {
    __shared__ __align__(16) char smem[34816];   // union: bin 30.8 KB / gemm 34.8 KB
    int b = blockIdx.x;
    if (b % 3 == 0) {                            // 782 bin blocks
        bin_block(b / 3, ev, flag, cursor, ebuf, smem);
    } else {
        int gid = b - b / 3 - 1;                 // 0..1562
        if (gid < NGEMM1) gemm1_block(gid, x, W1, h1raw, smem);
    }
}

// ---------------- per-bucket 256-bin counting sort -> split CSR + dinv + h1 scale ----------------
// bin = (dlow<<1) | (src >= NHALF): per-node sublist A (src<50k) then B.
__global__ __launch_bounds__(256) void k_sort(const unsigned* __restrict__ ebuf,
                                              const int* __restrict__ cursor,
                                              unsigned* __restrict__ srcs,
                                              int* __restrict__ startp,
                                              int* __restrict__ midp,
                                              int* __restrict__ endp,
                                              float* __restrict__ dinv,
                                              const unsigned* __restrict__ h1raw,
                                              unsigned* __restrict__ h1b) {
    __shared__ unsigned el[CAP];
    __shared__ unsigned so[CAP];
    __shared__ int hist[256];
    __shared__ int sc[256];
    __shared__ int off[256];
    __shared__ float dnl[BSZ];
    int b = blockIdx.x, t = threadIdx.x;
    hist[t] = 0;
    __syncthreads();
    int gs = b * CAP;
    int n = cursor[b] - gs;
    for (int i = t; i < n; i += 256) {
        unsigned e = ebuf[gs + i];
        el[i] = e;
        int bin = ((e & 127) << 1) | ((e >> 7) >= NHALF);
        atomicAdd(&hist[bin], 1);
    }
    __syncthreads();
    sc[t] = hist[t];
    __syncthreads();
    for (int o = 1; o < 256; o <<= 1) {            // Hillis-Steele inclusive
        int v = (t >= o) ? sc[t - o] : 0;
        __syncthreads();
        if (t >= o) sc[t] += v;
        __syncthreads();
    }
    off[t] = sc[t] - hist[t];                      // exclusive prefix
    if (t < BSZ) {
        int binA = t << 1, binB = binA | 1;
        int exA = sc[binA] - hist[binA];
        int cnt = sc[binB] - exA;
        float dn = rsqrtf((float)(cnt + 1));       // +1 self-loop
        dnl[t] = dn;
        int node = b * BSZ + t;
        if (node < NN) {
            startp[node] = gs + exA;
            midp[node]   = gs + sc[binA];
            endp[node]   = gs + sc[binB];
            dinv[node]   = dn;
        }
    }
    __syncthreads();
    for (int i = t; i < n; i += 256) {
        unsigned e = el[i];
        int bin = ((e & 127) << 1) | ((e >> 7) >= NHALF);
        int p = atomicAdd(&off[bin], 1);
        so[p] = e >> 7;
    }
    __syncthreads();
    for (int i = t; i < n; i += 256)
        srcs[gs + i] = so[i];
    // ---- scale tail: h1b = bf16(dinv[row] * h1raw) for this bucket's 128 rows ----
    for (int i = t; i < BSZ * 32; i += 256) {
        int row = i >> 5;
        int node = b * BSZ + row;
        if (node < NN) {
            unsigned wv = h1raw[(size_t)(b * BSZ) * 32 + i];
            float dn = dnl[row];
            float lo = __uint_as_float(wv << 16) * dn;
            float hi = __uint_as_float(wv & 0xffff0000u) * dn;
            h1b[(size_t)(b * BSZ) * 32 + i] = bf16_rne(lo) | (bf16_rne(hi) << 16);
        }
    }
}

// ---------------- agg1 pass A: sources < NHALF (ws = 6.4 MB/2) -> fp32 partials ----------------
__global__ __launch_bounds__(256) void k_agg1A(const unsigned* __restrict__ h1b,
                                               const int* __restrict__ startp,
                                               const int* __restrict__ midp,
                                               const unsigned* __restrict__ srcs,
                                               float* __restrict__ h1acc) {
    int wave = threadIdx.x >> 6, lane = threadIdx.x & 63;
    int half = lane >> 5, c = lane & 31;
    for (int it = 0; it < 4; ++it) {
        int node = blockIdx.x * 4 + wave + it * 25000;
        float a0 = 0.0f, a1 = 0.0f;
        if (half == 0) {                              // self term
            unsigned wv = h1b[(size_t)node * 32 + c];
            a0 = __uint_as_float(wv << 16);
            a1 = __uint_as_float(wv & 0xffff0000u);
        }
        int i = startp[node], end = midp[node];
        for (; i + 7 < end; i += 8) {
            int s0 = srcs[i + half],     s1 = srcs[i + 2 + half];
            int s2 = srcs[i + 4 + half], s3 = srcs[i + 6 + half];
            unsigned w0 = h1b[(size_t)s0 * 32 + c];
            unsigned w1 = h1b[(size_t)s1 * 32 + c];
            unsigned w2 = h1b[(size_t)s2 * 32 + c];
            unsigned w3 = h1b[(size_t)s3 * 32 + c];
            a0 += __uint_as_float(w0 << 16); a1 += __uint_as_float(w0 & 0xffff0000u);
            a0 += __uint_as_float(w1 << 16); a1 += __uint_as_float(w1 & 0xffff0000u);
            a0 += __uint_as_float(w2 << 16); a1 += __uint_as_float(w2 & 0xffff0000u);
            a0 += __uint_as_float(w3 << 16); a1 += __uint_as_float(w3 & 0xffff0000u);
        }
        for (; i + 1 < end; i += 2) {
            unsigned wv = h1b[(size_t)srcs[i + half] * 32 + c];
            a0 += __uint_as_float(wv << 16); a1 += __uint_as_float(wv & 0xffff0000u);
        }
        if (i < end && half == 0) {
            unsigned wv = h1b[(size_t)srcs[i] * 32 + c];
            a0 += __uint_as_float(wv << 16); a1 += __uint_as_float(wv & 0xffff0000u);
        }
        a0 += __shfl_xor(a0, 32, 64);
        a1 += __shfl_xor(a1, 32, 64);
        if (half == 0)
            *(float2*)&h1acc[(size_t)node * 64 + 2 * c] = make_float2(a0, a1);
    }
}

// ---------------- agg1 pass B: sources >= NHALF + relu + fused GEMV -> bf16 h2 ----------------
__global__ __launch_bounds__(256) void k_agg1B(const unsigned* __restrict__ h1b,
                                               const int* __restrict__ midp,
                                               const int* __restrict__ endp,
                                               const unsigned* __restrict__ srcs,
                                               const float* __restrict__ dinv,
                                               const float* __restrict__ b1,
                                               const float* __restrict__ W2,
                                               const float* __restrict__ h1acc,
                                               unsigned* __restrict__ h2b) {
    __shared__ float W2s[HID * ODIM];     // 8 KB
    __shared__ float ow[4][HID];          // wave-private o-row
    int t = threadIdx.x;
#pragma unroll
    for (int j = 0; j < 2; ++j) {
        int fid = j * 256 + t;
        *(float4*)&W2s[fid * 4] = *(const float4*)&W2[fid * 4];
    }
    __syncthreads();
    int wave = t >> 6, lane = t & 63;
    int half = lane >> 5, c = lane & 31;
    float2 bb = *(const float2*)&b1[2 * c];
    for (int it = 0; it < 4; ++it) {
        int node = blockIdx.x * 4 + wave + it * 25000;
        float dn = dinv[node];
        float a0 = 0.0f, a1 = 0.0f;
        if (half == 0) {                              // pass-A partials
            float2 ld = *(const float2*)&h1acc[(size_t)node * 64 + 2 * c];
            a0 = ld.x; a1 = ld.y;
        }
        int i = midp[node], end = endp[node];
        for (; i + 7 < end; i += 8) {
            int s0 = srcs[i + half],     s1 = srcs[i + 2 + half];
            int s2 = srcs[i + 4 + half], s3 = srcs[i + 6 + half];
            unsigned w0 = h1b[(size_t)s0 * 32 + c];
            unsigned w1 = h1b[(size_t)s1 * 32 + c];
            unsigned w2 = h1b[(size_t)s2 * 32 + c];
            unsigned w3 = h1b[(size_t)s3 * 32 + c];
            a0 += __uint_as_float(w0 << 16); a1 += __uint_as_float(w0 & 0xffff0000u);
            a0 += __uint_as_float(w1 << 16); a1 += __uint_as_float(w1 & 0xffff0000u);
            a0 += __uint_as_float(w2 << 16); a1 += __uint_as_float(w2 & 0xffff0000u);
            a0 += __uint_as_float(w3 << 16); a1 += __uint_as_float(w3 & 0xffff0000u);
        }
        for (; i + 1 < end; i += 2) {
            unsigned wv = h1b[(size_t)srcs[i + half] * 32 + c];
            a0 += __uint_as_float(wv << 16); a1 += __uint_as_float(wv & 0xffff0000u);
        }
        if (i < end && half == 0) {
            unsigned wv = h1b[(size_t)srcs[i] * 32 + c];
            a0 += __uint_as_float(wv << 16); a1 += __uint_as_float(wv & 0xffff0000u);
        }
        a0 += __shfl_xor(a0, 32, 64);
        a1 += __shfl_xor(a1, 32, 64);
        float o0 = dn * a0 + bb.x; o0 = o0 > 0.0f ? o0 : 0.0f;
        float o1v = dn * a1 + bb.y; o1v = o1v > 0.0f ? o1v : 0.0f;
        if (half == 0) *(float2*)&ow[wave][2 * c] = make_float2(o0, o1v);
        float ph = 0.0f;
#pragma unroll 8
        for (int k = 0; k < 32; ++k) {
            int kk = half * 32 + k;
            ph = fmaf(ow[wave][kk], W2s[kk * ODIM + c], ph);
        }
        ph += __shfl_xor(ph, 32, 64);
        float v = dn * ph;
        float vn = __shfl_xor(v, 1, 64);
        if (half == 0 && (c & 1) == 0)
            h2b[(size_t)node * 16 + (c >> 1)] = bf16_rne(v) | (bf16_rne(vn) << 16);
    }
}

// ---------------- agg2 pass A: sources < NHALF -> fp32 partials ----------------
__global__ __launch_bounds__(256) void k_agg2A(const unsigned* __restrict__ h2b,
                                               const int* __restrict__ startp,
                                               const int* __restrict__ midp,
                                               const unsigned* __restrict__ srcs,
                                               float* __restrict__ zacc) {
    int wave = threadIdx.x >> 6, lane = threadIdx.x & 63;
    int node = blockIdx.x * 4 + wave;
    int g = lane >> 4, cc = lane & 15;
    float a0 = 0.0f, a1 = 0.0f;
    if (g == 0) {                                     // self term
        unsigned wv = h2b[(size_t)node * 16 + cc];
        a0 = __uint_as_float(wv << 16);
        a1 = __uint_as_float(wv & 0xffff0000u);
    }
    int i = startp[node], end = midp[node];
    for (; i + 7 < end; i += 8) {
        int s0 = srcs[i + g], s1 = srcs[i + 4 + g];
        unsigned w0 = h2b[(size_t)s0 * 16 + cc];
        unsigned w1 = h2b[(size_t)s1 * 16 + cc];
        a0 += __uint_as_float(w0 << 16); a1 += __uint_as_float(w0 & 0xffff0000u);
        a0 += __uint_as_float(w1 << 16); a1 += __uint_as_float(w1 & 0xffff0000u);
    }
    for (; i + g < end; i += 4) {
        unsigned wv = h2b[(size_t)srcs[i + g] * 16 + cc];
        a0 += __uint_as_float(wv << 16); a1 += __uint_as_float(wv & 0xffff0000u);
    }
    a0 += __shfl_xor(a0, 16, 64); a0 += __shfl_xor(a0, 32, 64);
    a1 += __shfl_xor(a1, 16, 64); a1 += __shfl_xor(a1, 32, 64);
    if (lane < 16)
        *(float2*)&zacc[(size_t)node * 32 + 2 * cc] = make_float2(a0, a1);
}

// ---------------- agg2 pass B: sources >= NHALF + bias -> z ----------------
__global__ __launch_bounds__(256) void k_agg2B(const unsigned* __restrict__ h2b,
                                               const int* __restrict__ midp,
                                               const int* __restrict__ endp,
                                               const unsigned* __restrict__ srcs,
                                               const float* __restrict__ dinv,
                                               const float* __restrict__ b2,
                                               const float* __restrict__ zacc,
                                               float* __restrict__ z) {
    int wave = threadIdx.x >> 6, lane = threadIdx.x & 63;
    int node = blockIdx.x * 4 + wave;
    int g = lane >> 4, cc = lane & 15;
    float2 bb = *(const float2*)&b2[2 * cc];
    float a0 = 0.0f, a1 = 0.0f;
    if (g == 0) {                                     // pass-A partials
        float2 ld = *(const float2*)&zacc[(size_t)node * 32 + 2 * cc];
        a0 = ld.x; a1 = ld.y;
    }
    int i = midp[node], end = endp[node];
    for (; i + 7 < end; i += 8) {
        int s0 = srcs[i + g], s1 = srcs[i + 4 + g];
        unsigned w0 = h2b[(size_t)s0 * 16 + cc];
        unsigned w1 = h2b[(size_t)s1 * 16 + cc];
        a0 += __uint_as_float(w0 << 16); a1 += __uint_as_float(w0 & 0xffff0000u);
        a0 += __uint_as_float(w1 << 16); a1 += __uint_as_float(w1 & 0xffff0000u);
    }
    for (; i + g < end; i += 4) {
        unsigned wv = h2b[(size_t)srcs[i + g] * 16 + cc];
        a0 += __uint_as_float(wv << 16); a1 += __uint_as_float(wv & 0xffff0000u);
    }
    a0 += __shfl_xor(a0, 16, 64); a0 += __shfl_xor(a0, 32, 64);
    a1 += __shfl_xor(a1, 16, 64); a1 += __shfl_xor(a1, 32, 64);
    if (lane < 16) {
        float dn = dinv[node];
        *(float2*)&z[(size_t)node * ODIM + 2 * cc] =
            make_float2(dn * a0 + bb.x, dn * a1 + bb.y);
    }
}

extern "C" void kernel_launch(void* const* d_in, const int* in_sizes, int n_in,
                              void* d_out, int out_size, void* d_ws, size_t ws_size,
                              hipStream_t stream) {
    const float* x  = (const float*)d_in[0];
    const void*  ei = d_in[1];
    const float* W1 = (const float*)d_in[2];
    const float* b1 = (const float*)d_in[3];
    const float* W2 = (const float*)d_in[4];
    const float* b2 = (const float*)d_in[5];
    float* z = (float*)d_out;

    char* w = (char*)d_ws;
    auto alloc = [&](size_t bytes) -> void* {
        void* p = (void*)w;
        w += (bytes + 255) & ~(size_t)255;
        return p;
    };
    int*      flag   = (int*)     alloc(sizeof(int));
    int*      cursor = (int*)     alloc(sizeof(int) * NB);
    float*    dinv   = (float*)   alloc(sizeof(float) * NN);
    int*      startp = (int*)     alloc(sizeof(int) * NN);
    int*      midp   = (int*)     alloc(sizeof(int) * NN);
    int*      endp   = (int*)     alloc(sizeof(int) * NN);
    unsigned* ebuf   = (unsigned*)alloc(sizeof(unsigned) * (size_t)NB * CAP); // 14.4 MB
    unsigned* srcs   = (unsigned*)alloc(sizeof(unsigned) * (size_t)NB * CAP); // 14.4 MB
    unsigned* h1raw  = (unsigned*)alloc(sizeof(unsigned) * (size_t)NN * 32);  // 12.8 MB
    unsigned* h1b    = (unsigned*)alloc(sizeof(unsigned) * (size_t)NN * 32);  // 12.8 MB
    float*    h1acc  = (float*)   alloc(sizeof(float) * (size_t)NN * 64);     // 25.6 MB
    unsigned* h2b    = h1raw;             // h1raw dead after k_sort; 6.4 <= 12.8 MB
    float*    zacc   = (float*)ebuf;      // ebuf dead after k_sort; 12.8 <= 14.4 MB
    (void)ws_size; (void)in_sizes; (void)n_in; (void)out_size;                // ~82 MB

    hipMemsetAsync(flag, 0, sizeof(int), stream);

    k_detect <<<1, 256, 0, stream>>>((const unsigned*)ei, flag);
    k_initcur<<<(NB + 255) / 256, 256, 0, stream>>>(cursor);
    k_fuse1  <<<NBIN + NGEMM1, 256, 0, stream>>>(x, W1, h1raw, ei, flag, cursor, ebuf);
    k_sort   <<<NB, 256, 0, stream>>>(ebuf, cursor, srcs, startp, midp, endp, dinv, h1raw, h1b);
    k_agg1A  <<<6250, 256, 0, stream>>>(h1b, startp, midp, srcs, h1acc);
    k_agg1B  <<<6250, 256, 0, stream>>>(h1b, midp, endp, srcs, dinv, b1, W2, h1acc, h2b);
    k_agg2A  <<<NN / 4, 256, 0, stream>>>(h2b, startp, midp, srcs, zacc);
    k_agg2B  <<<NN / 4, 256, 0, stream>>>(h2b, midp, endp, srcs, dinv, b2, zacc, z);
}

// Round 9
// 388.929 us; speedup vs baseline: 1.0852x; 1.0852x over previous
//
#include <hip/hip_runtime.h>

#define NN      100000
#define NE      3200000
#define IN_DIM  256
#define HID     64
#define ODIM    32
#define BSZ     128                 // nodes per bucket (dst>>7)
#define NB      782                 // ceil(NN / BSZ)
#define CAP     4608                // max edges/bucket: mean 4096, sd ~64 -> +8 sigma
#define CHUNK   4096                // edges per binning block
#define NGEMM1  1563                // ceil(NN / 64)
#define NBIN    782                 // ceil(NE / CHUNK)
#define QDIV    25000u              // src quartile width (3.2 MB h1b slice < 4 MB XCD L2)

typedef __attribute__((ext_vector_type(8))) short bf16x8;
typedef __attribute__((ext_vector_type(4))) float f32x4;

__device__ __forceinline__ unsigned bf16_rne(float f) {
    unsigned u = __float_as_uint(f);
    return (u + 0x7fffu + ((u >> 16) & 1u)) >> 16;
}

// ---------------- detect int64 vs int32 + init cursor (1 block) ----------------
__global__ void k_detect(const unsigned* __restrict__ e, int* __restrict__ flag,
                         int* __restrict__ cursor) {
    __shared__ int f;
    if (threadIdx.x == 0) f = 0;
    __syncthreads();
    unsigned d = e[2u * threadIdx.x + 1u];
    if (d != 0u) atomicOr(&f, 1);      // any nonzero high-dword => int32 layout
    __syncthreads();
    if (threadIdx.x == 0) *flag = f;
    for (int i = threadIdx.x; i < NB; i += 256) cursor[i] = i * CAP;
}

// ---------------- fused kernel 1: MFMA GEMM1 blocks + bin blocks ----------------
__device__ void bin_block(int bb, const void* __restrict__ ev, const int* __restrict__ flag,
                          int* __restrict__ cursor, unsigned* __restrict__ ebuf, char* smem) {
    unsigned* el        = (unsigned*)smem;                 // [4096] 16 KB packed
    unsigned short* bk  = (unsigned short*)(smem + 16384); // [4096]  8 KB bucket ids
    int* hist           = (int*)(smem + 24576);            // [782]
    int* gbase          = (int*)(smem + 27712);            // [782]  => 30.8 KB
    int t = threadIdx.x;
    for (int i = t; i < NB; i += 256) hist[i] = 0;
    __syncthreads();
    bool is64 = (*flag == 0);
    long long base = (long long)bb * CHUNK;
#pragma unroll
    for (int j = 0; j < CHUNK / 256; ++j) {
        int li = j * 256 + t;
        long long idx = base + li;
        if (idx < NE) {
            int s, d;
            if (is64) {
                s = (int)((const long long*)ev)[idx];
                d = (int)((const long long*)ev)[NE + idx];
            } else {
                s = ((const int*)ev)[idx];
                d = ((const int*)ev)[NE + idx];
            }
            el[li] = ((unsigned)s << 7) | (unsigned)(d & 127);
            int bu = d >> 7;
            bk[li] = (unsigned short)bu;
            atomicAdd(&hist[bu], 1);
        }
    }
    __syncthreads();
    for (int u = t; u < NB; u += 256) {
        int c = hist[u];
        gbase[u] = c ? atomicAdd(&cursor[u], c) : 0;   // claim contiguous run
        hist[u] = 0;                                   // reuse as local offset
    }
    __syncthreads();
#pragma unroll
    for (int j = 0; j < CHUNK / 256; ++j) {
        int li = j * 256 + t;
        long long idx = base + li;
        if (idx < NE) {
            int bu = bk[li];
            int p = gbase[bu] + atomicAdd(&hist[bu], 1);
            if (p < (bu + 1) * CAP)                    // safety; never triggers
                ebuf[p] = el[li];
        }
    }
}

// MFMA GEMM: 64x64 tile, K-tile 128, wave w owns rows 16w..16w+15, 4 col-frags.
#define LSTR 136
__device__ void gemm1_block(int gid, const float* __restrict__ x,
                            const float* __restrict__ W1, unsigned* __restrict__ h1raw,
                            char* smem) {
    short* xs = (short*)smem;              // 17408 B
    short* wt = (short*)(smem + 17408);    // 17408 B => 34816 B total
    int t = threadIdx.x;
    int w = t >> 6, l = t & 63;
    int l15 = l & 15, g = l >> 4;
    int rowBase = gid * 64;
    f32x4 acc[4];
#pragma unroll
    for (int ct = 0; ct < 4; ++ct) acc[ct] = (f32x4){0.f, 0.f, 0.f, 0.f};

    for (int kt = 0; kt < IN_DIM; kt += 128) {
        __syncthreads();
#pragma unroll
        for (int p = 0; p < 8; ++p) {          // stage x: 64 rows x 128 k -> bf16
            int fid = p * 256 + t;
            int r = fid >> 5, c4 = fid & 31;
            int gr = rowBase + r; if (gr >= NN) gr = NN - 1;
            float4 v = *(const float4*)&x[(size_t)gr * IN_DIM + kt + c4 * 4];
            *(unsigned*)&xs[r * LSTR + c4 * 4]     = bf16_rne(v.x) | (bf16_rne(v.y) << 16);
            *(unsigned*)&xs[r * LSTR + c4 * 4 + 2] = bf16_rne(v.z) | (bf16_rne(v.w) << 16);
        }
#pragma unroll
        for (int p = 0; p < 8; ++p) {          // stage W1^T
            int n = t & 63, kb = (t >> 6) * 4 + p * 16;
            float v0 = W1[(size_t)(kt + kb + 0) * HID + n];
            float v1 = W1[(size_t)(kt + kb + 1) * HID + n];
            float v2 = W1[(size_t)(kt + kb + 2) * HID + n];
            float v3 = W1[(size_t)(kt + kb + 3) * HID + n];
            *(unsigned*)&wt[n * LSTR + kb]     = bf16_rne(v0) | (bf16_rne(v1) << 16);
            *(unsigned*)&wt[n * LSTR + kb + 2] = bf16_rne(v2) | (bf16_rne(v3) << 16);
        }
        __syncthreads();
#pragma unroll
        for (int step = 0; step < 4; ++step) { // K=32 per step
            int ko = step * 32 + g * 8;
            bf16x8 a = *(const bf16x8*)&xs[(w * 16 + l15) * LSTR + ko];
#pragma unroll
            for (int ct = 0; ct < 4; ++ct) {
                bf16x8 b = *(const bf16x8*)&wt[(ct * 16 + l15) * LSTR + ko];
                acc[ct] = __builtin_amdgcn_mfma_f32_16x16x32_bf16(a, b, acc[ct], 0, 0, 0);
            }
        }
    }
    // D: row=(l>>4)*4+reg, col=ct*16+(l&15); pack bf16 pairs via neighbor shfl
#pragma unroll
    for (int ct = 0; ct < 4; ++ct) {
#pragma unroll
        for (int r = 0; r < 4; ++r) {
            float v = acc[ct][r];
            float vn = __shfl_xor(v, 1, 64);
            int gr = rowBase + w * 16 + g * 4 + r;
            if ((l15 & 1) == 0 && gr < NN)
                h1raw[(size_t)gr * 32 + ct * 8 + (l15 >> 1)] =
                    bf16_rne(v) | (bf16_rne(vn) << 16);
        }
    }
}

__global__ __launch_bounds__(256, 4) void k_fuse1(const float* __restrict__ x,
                                                  const float* __restrict__ W1,
                                                  unsigned* __restrict__ h1raw,
                                                  const void* __restrict__ ev,
                                                  const int* __restrict__ flag,
                                                  int* __restrict__ cursor,
                                                  unsigned* __restrict__ ebuf) {
    __shared__ __align__(16) char smem[34816];   // union: bin 30.8 KB / gemm 34.8 KB
    int b = blockIdx.x;
    if (b % 3 == 0) {                            // 782 bin blocks
        bin_block(b / 3, ev, flag, cursor, ebuf, smem);
    } else {
        int gid = b - b / 3 - 1;                 // 0..1562
        if (gid < NGEMM1) gemm1_block(gid, x, W1, h1raw, smem);
    }
}

// ---------------- per-bucket 512-bin counting sort -> CSR (src-quartile ordered) ----------------
// key = (dlow<<2) | src/25000: per-node edge list ordered by src quartile, so all
// resident agg waves sweep quartile q together -> 3.2 MB gather slice fits XCD L2.
__global__ __launch_bounds__(256) void k_sort(const unsigned* __restrict__ ebuf,
                                              const int* __restrict__ cursor,
                                              unsigned* __restrict__ srcs,
                                              int* __restrict__ startp,
                                              int* __restrict__ endp,
                                              float* __restrict__ dinv,
                                              const unsigned* __restrict__ h1raw,
                                              unsigned* __restrict__ h1b) {
    __shared__ unsigned el[CAP];      // 18.4 KB
    __shared__ unsigned so[CAP];      // 18.4 KB
    __shared__ int hist[512];
    __shared__ int sc[512];           // inclusive prefix (immutable)
    __shared__ int off[512];          // running exclusive (mutated by scatter)
    __shared__ int pp[256];           // pair-sum scan
    __shared__ float dnl[BSZ];
    int b = blockIdx.x, t = threadIdx.x;
    hist[t] = 0; hist[t + 256] = 0;
    __syncthreads();
    int gs = b * CAP;
    int n = cursor[b] - gs;
    for (int i = t; i < n; i += 256) {
        unsigned e = ebuf[gs + i];
        el[i] = e;
        unsigned q = (e >> 7) / QDIV;
        atomicAdd(&hist[((e & 127) << 2) | q], 1);
    }
    __syncthreads();
    int a0 = hist[2 * t], a1 = hist[2 * t + 1];
    pp[t] = a0 + a1;
    __syncthreads();
    for (int o = 1; o < 256; o <<= 1) {            // Hillis-Steele over pair sums
        int v = (t >= o) ? pp[t - o] : 0;
        __syncthreads();
        if (t >= o) pp[t] += v;
        __syncthreads();
    }
    int exPair = pp[t] - (a0 + a1);
    off[2 * t]     = exPair;
    off[2 * t + 1] = exPair + a0;
    sc[2 * t]      = exPair + a0;
    sc[2 * t + 1]  = exPair + a0 + a1;
    __syncthreads();
    if (t < BSZ) {
        int st = sc[4 * t] - hist[4 * t];          // exclusive of node's first bin
        int en = sc[4 * t + 3];                    // inclusive of node's last bin
        float dn = rsqrtf((float)(en - st + 1));   // +1 self-loop
        dnl[t] = dn;
        int node = b * BSZ + t;
        if (node < NN) {
            startp[node] = gs + st;
            endp[node]   = gs + en;
            dinv[node]   = dn;
        }
    }
    __syncthreads();
    for (int i = t; i < n; i += 256) {
        unsigned e = el[i];
        unsigned q = (e >> 7) / QDIV;
        int p = atomicAdd(&off[((e & 127) << 2) | q], 1);
        so[p] = e >> 7;
    }
    __syncthreads();
    for (int i = t; i < n; i += 256)
        srcs[gs + i] = so[i];
    // ---- scale tail: h1b = bf16(dinv[row] * h1raw) for this bucket's 128 rows ----
    for (int i = t; i < BSZ * 32; i += 256) {
        int row = i >> 5;
        int node = b * BSZ + row;
        if (node < NN) {
            unsigned wv = h1raw[(size_t)(b * BSZ) * 32 + i];
            float dn = dnl[row];
            float lo = __uint_as_float(wv << 16) * dn;
            float hi = __uint_as_float(wv & 0xffff0000u) * dn;
            h1b[(size_t)(b * BSZ) * 32 + i] = bf16_rne(lo) | (bf16_rne(hi) << 16);
        }
    }
}

// ---------------- agg1 + relu + fused GEMV, bf16 gather (src-quartile ordered list) ----------------
__global__ __launch_bounds__(256) void k_agg1f(const unsigned* __restrict__ h1b,
                                               const int* __restrict__ startp,
                                               const int* __restrict__ endp,
                                               const unsigned* __restrict__ srcs,
                                               const float* __restrict__ dinv,
                                               const float* __restrict__ b1,
                                               const float* __restrict__ W2,
                                               unsigned* __restrict__ h2b) {
    __shared__ float W2s[HID * ODIM];     // 8 KB
    __shared__ float ow[4][HID];          // wave-private o-row (wave-synchronous)
    int t = threadIdx.x;
#pragma unroll
    for (int j = 0; j < 2; ++j) {
        int fid = j * 256 + t;
        *(float4*)&W2s[fid * 4] = *(const float4*)&W2[fid * 4];
    }
    __syncthreads();
    int wave = t >> 6, lane = t & 63;
    int half = lane >> 5, c = lane & 31;
    float2 bb = *(const float2*)&b1[2 * c];
    int node = blockIdx.x * 4 + wave;          // 25000*4 = NN exactly
    float dn = dinv[node];
    float a0 = 0.0f, a1 = 0.0f;
    if (half == 0) {                           // self term once
        unsigned wv = h1b[(size_t)node * 32 + c];
        a0 = __uint_as_float(wv << 16);
        a1 = __uint_as_float(wv & 0xffff0000u);
    }
    int i = startp[node], end = endp[node];
    for (; i + 7 < end; i += 8) {              // 4 edges per half in flight
        int s0 = srcs[i + half],     s1 = srcs[i + 2 + half];
        int s2 = srcs[i + 4 + half], s3 = srcs[i + 6 + half];
        unsigned w0 = h1b[(size_t)s0 * 32 + c];
        unsigned w1 = h1b[(size_t)s1 * 32 + c];
        unsigned w2 = h1b[(size_t)s2 * 32 + c];
        unsigned w3 = h1b[(size_t)s3 * 32 + c];
        a0 += __uint_as_float(w0 << 16); a1 += __uint_as_float(w0 & 0xffff0000u);
        a0 += __uint_as_float(w1 << 16); a1 += __uint_as_float(w1 & 0xffff0000u);
        a0 += __uint_as_float(w2 << 16); a1 += __uint_as_float(w2 & 0xffff0000u);
        a0 += __uint_as_float(w3 << 16); a1 += __uint_as_float(w3 & 0xffff0000u);
    }
    for (; i + 1 < end; i += 2) {
        unsigned wv = h1b[(size_t)srcs[i + half] * 32 + c];
        a0 += __uint_as_float(wv << 16); a1 += __uint_as_float(wv & 0xffff0000u);
    }
    if (i < end && half == 0) {                // odd tail
        unsigned wv = h1b[(size_t)srcs[i] * 32 + c];
        a0 += __uint_as_float(wv << 16); a1 += __uint_as_float(wv & 0xffff0000u);
    }
    a0 += __shfl_xor(a0, 32, 64);              // combine halves
    a1 += __shfl_xor(a1, 32, 64);
    float o0 = dn * a0 + bb.x; o0 = o0 > 0.0f ? o0 : 0.0f;
    float o1v = dn * a1 + bb.y; o1v = o1v > 0.0f ? o1v : 0.0f;
    if (half == 0) *(float2*)&ow[wave][2 * c] = make_float2(o0, o1v);
    // GEMV: halves split k, xor-combine; pack feature pairs to bf16
    float ph = 0.0f;
#pragma unroll 8
    for (int k = 0; k < 32; ++k) {
        int kk = half * 32 + k;
        ph = fmaf(ow[wave][kk], W2s[kk * ODIM + c], ph);
    }
    ph += __shfl_xor(ph, 32, 64);
    float v = dn * ph;                         // h2' feature c (both halves)
    float vn = __shfl_xor(v, 1, 64);           // feature c^1
    if (half == 0 && (c & 1) == 0)
        h2b[(size_t)node * 16 + (c >> 1)] = bf16_rne(v) | (bf16_rne(vn) << 16);
}

// ---------------- conv2 aggregate: 16 lanes/edge, 4 edges/wave, 2x unroll ----------------
__global__ __launch_bounds__(256) void k_agg2(const unsigned* __restrict__ h2b,
                                              const int* __restrict__ startp,
                                              const int* __restrict__ endp,
                                              const unsigned* __restrict__ srcs,
                                              const float* __restrict__ dinv,
                                              const float* __restrict__ b2,
                                              float* __restrict__ z) {
    int wave = threadIdx.x >> 6, lane = threadIdx.x & 63;
    int node = blockIdx.x * 4 + wave;          // 25000*4 = NN exactly
    int g = lane >> 4, cc = lane & 15;
    float2 bb = *(const float2*)&b2[2 * cc];
    float a0 = 0.0f, a1 = 0.0f;
    if (g == 0) {                              // self term
        unsigned wv = h2b[(size_t)node * 16 + cc];
        a0 = __uint_as_float(wv << 16);
        a1 = __uint_as_float(wv & 0xffff0000u);
    }
    int i = startp[node], end = endp[node];
    for (; i + 7 < end; i += 8) {              // 2 edges per group in flight
        int s0 = srcs[i + g], s1 = srcs[i + 4 + g];
        unsigned w0 = h2b[(size_t)s0 * 16 + cc];
        unsigned w1 = h2b[(size_t)s1 * 16 + cc];
        a0 += __uint_as_float(w0 << 16); a1 += __uint_as_float(w0 & 0xffff0000u);
        a0 += __uint_as_float(w1 << 16); a1 += __uint_as_float(w1 & 0xffff0000u);
    }
    for (; i + g < end; i += 4) {
        unsigned wv = h2b[(size_t)srcs[i + g] * 16 + cc];
        a0 += __uint_as_float(wv << 16); a1 += __uint_as_float(wv & 0xffff0000u);
    }
    a0 += __shfl_xor(a0, 16, 64); a0 += __shfl_xor(a0, 32, 64);
    a1 += __shfl_xor(a1, 16, 64); a1 += __shfl_xor(a1, 32, 64);
    if (lane < 16) {
        float dn = dinv[node];
        *(float2*)&z[(size_t)node * ODIM + 2 * cc] =
            make_float2(dn * a0 + bb.x, dn * a1 + bb.y);
    }
}

extern "C" void kernel_launch(void* const* d_in, const int* in_sizes, int n_in,
                              void* d_out, int out_size, void* d_ws, size_t ws_size,
                              hipStream_t stream) {
    const float* x  = (const float*)d_in[0];
    const void*  ei = d_in[1];
    const float* W1 = (const float*)d_in[2];
    const float* b1 = (const float*)d_in[3];
    const float* W2 = (const float*)d_in[4];
    const float* b2 = (const float*)d_in[5];
    float* z = (float*)d_out;

    char* w = (char*)d_ws;
    auto alloc = [&](size_t bytes) -> void* {
        void* p = (void*)w;
        w += (bytes + 255) & ~(size_t)255;
        return p;
    };
    int*      flag   = (int*)     alloc(sizeof(int));
    int*      cursor = (int*)     alloc(sizeof(int) * NB);
    float*    dinv   = (float*)   alloc(sizeof(float) * NN);
    int*      startp = (int*)     alloc(sizeof(int) * NN);
    int*      endp   = (int*)     alloc(sizeof(int) * NN);
    unsigned* ebuf   = (unsigned*)alloc(sizeof(unsigned) * (size_t)NB * CAP); // 14.4 MB
    unsigned* srcs   = (unsigned*)alloc(sizeof(unsigned) * (size_t)NB * CAP); // 14.4 MB
    unsigned* h1raw  = (unsigned*)alloc(sizeof(unsigned) * (size_t)NN * 32);  // 12.8 MB
    unsigned* h1b    = (unsigned*)alloc(sizeof(unsigned) * (size_t)NN * 32);  // 12.8 MB
    unsigned* h2b    = h1raw;             // h1raw dead after k_sort; 6.4 <= 12.8 MB
    (void)ws_size; (void)in_sizes; (void)n_in; (void)out_size;                // ~56 MB

    k_detect<<<1, 256, 0, stream>>>((const unsigned*)ei, flag, cursor);
    k_fuse1 <<<NBIN + NGEMM1, 256, 0, stream>>>(x, W1, h1raw, ei, flag, cursor, ebuf);
    k_sort  <<<NB, 256, 0, stream>>>(ebuf, cursor, srcs, startp, endp, dinv, h1raw, h1b);
    k_agg1f <<<NN / 4, 256, 0, stream>>>(h1b, startp, endp, srcs, dinv, b1, W2, h2b);
    k_agg2  <<<NN / 4, 256, 0, stream>>>(h2b, startp, endp, srcs, dinv, b2, z);
}